// Round 7
// baseline (459.502 us; speedup 1.0000x reference)
//
#include <hip/hip_runtime.h>
#include <math.h>

typedef short short8 __attribute__((ext_vector_type(8)));
typedef float f32x4 __attribute__((ext_vector_type(4)));
typedef unsigned long long u64;

#define LOG2E 1.4426950408889634f

__device__ __forceinline__ unsigned short f2bf_rne(float f) {
    unsigned u = __float_as_uint(f);
    unsigned r = (u + 0x7fff + ((u >> 16) & 1)) >> 16;
    return (unsigned short)r;
}
__device__ __forceinline__ float bf2f(unsigned short h) {
    return __uint_as_float(((unsigned)h) << 16);
}
__device__ __forceinline__ void load_lds16(const void* g, void* l) {
    __builtin_amdgcn_global_load_lds((const __attribute__((address_space(1))) void*)g,
                                     (__attribute__((address_space(3))) void*)l,
                                     16, 0, 0);
}
__device__ __forceinline__ u64 pack8_fp8(const float* v, float s) {
    int lo = 0, hi = 0;
    lo = __builtin_amdgcn_cvt_pk_fp8_f32(v[0] * s, v[1] * s, lo, false);
    lo = __builtin_amdgcn_cvt_pk_fp8_f32(v[2] * s, v[3] * s, lo, true);
    hi = __builtin_amdgcn_cvt_pk_fp8_f32(v[4] * s, v[5] * s, hi, false);
    hi = __builtin_amdgcn_cvt_pk_fp8_f32(v[6] * s, v[7] * s, hi, true);
    return (u64)(unsigned)lo | ((u64)(unsigned)hi << 32);
}

// ---------------- fused prep (streaming convert) + projections ----------------
struct ProjDesc {
    const float* B;            // fp32 P matrix [N][1024]
    unsigned short* Cbf;       // bf16 Y [1024][ldc]
    unsigned char* Cf8;        // fp8 Y, granule-tile layout
    int ldc; int nreal; int N; int Kpad; int gy_begin;
};

__global__ __launch_bounds__(256) void prepproj(
    const float* __restrict__ hidden,
    ProjDesc p0, ProjDesc p1, ProjDesc p2, ProjDesc p3,
    const float* __restrict__ W0, const float* __restrict__ cw,
    const float* __restrict__ W1, const float* __restrict__ W2,
    const float* __restrict__ W3,
    const float* __restrict__ b0, const float* __restrict__ cb,
    const float* __restrict__ b1, const float* __restrict__ b2,
    const float* __restrict__ b3,
    unsigned char* __restrict__ Wb0, unsigned char* __restrict__ Wb1,
    unsigned char* __restrict__ Wb2, unsigned char* __restrict__ Wb3,
    float* __restrict__ bp)
{
    __shared__ char smem[34816];

    const int tid = threadIdx.x;
    const int bx = blockIdx.x;

    if (bx >= 96) {
        const int v = bx - 96;
        if (v < 9896) {
            // weight convert: unit = 16 floats -> 2 granules; r-fastest (coalesced writes)
            const float* src = nullptr;
            u64* dst;
            unsigned kseg, r;
            if (v < 5056) {            // W0 head: 158 tiles x 64 kseg x 128 r
                const unsigned u = v * 256u + tid;
                const unsigned tile = u >> 13; kseg = (u >> 7) & 63u; r = u & 127u;
                const unsigned row = tile * 128u + r;
                if (row < 20000u)      src = W0 + (size_t)row * 1024 + kseg * 16;
                else if (row < 20003u) src = cw + (size_t)(row - 20000u) * 1024 + kseg * 16;
                dst = (u64*)Wb0 + (size_t)tile * 16384;
            } else if (v < 6336) {     // W1: 160 tiles x 16 x 128
                const unsigned u = (v - 5056) * 256u + tid;
                const unsigned tile = u >> 11; kseg = (u >> 7) & 15u; r = u & 127u;
                const unsigned row = tile * 128u + r;
                if (row < 20000u) src = W1 + (size_t)row * 256 + kseg * 16;
                dst = (u64*)Wb1 + (size_t)tile * 4096;
            } else if (v < 8836) {     // W2: 1250 tiles x 4 x 128 (exact)
                const unsigned u = (v - 6336) * 256u + tid;
                const unsigned tile = u >> 9; kseg = (u >> 7) & 3u; r = u & 127u;
                src = W2 + (size_t)(tile * 128u + r) * 64 + kseg * 16;
                dst = (u64*)Wb2 + (size_t)tile * 1024;
            } else {                   // W3: 530 tiles x 4 x 128, real K=16 (kseg 0)
                const unsigned u = (v - 8836) * 256u + tid;
                const unsigned tile = u >> 9; kseg = (u >> 7) & 3u; r = u & 127u;
                const unsigned row = tile * 128u + r;
                if (kseg == 0 && row < 67735u) src = W3 + (size_t)row * 16;
                dst = (u64*)Wb3 + (size_t)tile * 1024;
            }
            float f[16];
            if (src) {
#pragma unroll
                for (int q = 0; q < 4; ++q) {
                    const float4 x = *(const float4*)(src + q * 4);
                    f[q * 4 + 0] = x.x; f[q * 4 + 1] = x.y;
                    f[q * 4 + 2] = x.z; f[q * 4 + 3] = x.w;
                }
            } else {
#pragma unroll
                for (int q = 0; q < 16; ++q) f[q] = 0.f;
            }
            dst[(2 * kseg) * 128 + r]     = pack8_fp8(f,     16.0f);
            dst[(2 * kseg + 1) * 128 + r] = pack8_fp8(f + 8, 16.0f);
        } else {
            // padded biases, pre-scaled by log2e; pad rows -> -1e30
            const unsigned u = (v - 9896) * 256u + tid;
            if (u < 67136u) {
                const unsigned idx0 = u * 4u;
                float e[4];
#pragma unroll
                for (int j = 0; j < 4; ++j) {
                    const unsigned idx = idx0 + j;
                    float x;
                    if (idx < 20224u) {
                        x = (idx < 20000u) ? b0[idx] * LOG2E
                          : (idx < 20003u) ? cb[idx - 20000u] * LOG2E : -1e30f;
                    } else if (idx < 40704u) {
                        const unsigned i1 = idx - 20224u;
                        x = (i1 < 20000u) ? b1[i1] * LOG2E : -1e30f;
                    } else if (idx < 200704u) {
                        x = b2[idx - 40704u] * LOG2E;
                    } else {
                        const unsigned i3 = idx - 200704u;
                        x = (i3 < 67735u) ? b3[i3] * LOG2E : -1e30f;
                    }
                    e[j] = x;
                }
                *(float4*)(bp + idx0) = make_float4(e[0], e[1], e[2], e[3]);
            }
        }
        return;
    }

    // ---------- projection GEMM path (A from fp32 hidden, B from fp32 P) ----------
    unsigned short* As = (unsigned short*)smem;            // [8192] bf16
    unsigned short* Bs = (unsigned short*)(smem + 16384);  // [8192] bf16

    const int mt = bx & 7;
    const int py = bx >> 3;
    ProjDesc p = (py >= p3.gy_begin) ? p3 : (py >= p2.gy_begin) ? p2
               : (py >= p1.gy_begin) ? p1 : p0;

    const int w = tid >> 6;
    const int l = tid & 63;
    const int m0 = mt * 128;
    const int n0 = (py - p.gy_begin) * 128;
    const int wm = (w >> 1) * 64;
    const int wn = (w & 1) * 64;
    const int lane16 = l & 15;
    const int quad = l >> 4;

    const int sn = tid >> 1;                  // staging row 0..127
    const int shalf = tid & 1;
    const float* arow_ptr = hidden + (size_t)(m0 + sn) * 1024;
    int brow = n0 + sn;
    if (brow > p.N - 1) brow = p.N - 1;
    const float* brow_ptr = p.B + (size_t)brow * 1024;

    f32x4 acc[4][4] = {};

    for (int k0 = 0; k0 < 1024; k0 += 64) {
        __syncthreads();
#pragma unroll
        for (int j = 0; j < 8; ++j) {
            const int kq = shalf * 8 + j;
            const int gran = (kq >> 1) * 128 + sn;
            {
                const float4 x = *(const float4*)(arow_ptr + k0 + kq * 4);
                const unsigned px = __builtin_amdgcn_perm(__float_as_uint(x.y), __float_as_uint(x.x), 0x07060302);
                const unsigned py2 = __builtin_amdgcn_perm(__float_as_uint(x.w), __float_as_uint(x.z), 0x07060302);
                *(uint2*)&As[gran * 8 + (kq & 1) * 4] = make_uint2(px, py2);
            }
            {
                const float4 x = *(const float4*)(brow_ptr + k0 + kq * 4);
                const unsigned px = __builtin_amdgcn_perm(__float_as_uint(x.y), __float_as_uint(x.x), 0x07060302);
                const unsigned py2 = __builtin_amdgcn_perm(__float_as_uint(x.w), __float_as_uint(x.z), 0x07060302);
                *(uint2*)&Bs[gran * 8 + (kq & 1) * 4] = make_uint2(px, py2);
            }
        }
        __syncthreads();

#pragma unroll
        for (int kk = 0; kk < 2; ++kk) {
            const int kgb = kk * 4 + quad;
            short8 af[4], bfr[4];
#pragma unroll
            for (int mi = 0; mi < 4; ++mi)
                af[mi] = *(const short8*)&As[(kgb * 128 + wm + mi * 16 + lane16) * 8];
#pragma unroll
            for (int ni = 0; ni < 4; ++ni)
                bfr[ni] = *(const short8*)&Bs[(kgb * 128 + wn + ni * 16 + lane16) * 8];
#pragma unroll
            for (int mi = 0; mi < 4; ++mi)
#pragma unroll
                for (int ni = 0; ni < 4; ++ni)
                    acc[mi][ni] = __builtin_amdgcn_mfma_f32_16x16x32_bf16(
                        af[mi], bfr[ni], acc[mi][ni], 0, 0, 0);
        }
    }

    // epilogue 1: bf16 Y store
#pragma unroll
    for (int mi = 0; mi < 4; ++mi)
#pragma unroll
        for (int ni = 0; ni < 4; ++ni) {
            const int n = n0 + wn + ni * 16 + lane16;
            if (n < p.ldc) {
#pragma unroll
                for (int r = 0; r < 4; ++r) {
                    const int m = m0 + wm + mi * 16 + quad * 4 + r;
                    const float x = (n < p.nreal) ? acc[mi][ni][r] : 0.f;
                    p.Cbf[(size_t)m * p.ldc + n] = f2bf_rne(x);
                }
            }
        }

    // epilogue 2: fp8 Y store in granule-tile layout (scale x4) via LDS bounce
    float* bounce = (float*)smem;                           // [128][66]
    u64* Yout = (u64*)p.Cf8 + (size_t)mt * 16 * p.Kpad;
    for (int c = 0; c < 2; ++c) {
        const int colbase = n0 + c * 64;
        if (colbase >= p.Kpad) break;
        __syncthreads();
        if ((w & 1) == c) {
#pragma unroll
            for (int mi = 0; mi < 4; ++mi)
#pragma unroll
                for (int ni = 0; ni < 4; ++ni) {
                    const int ncol = ni * 16 + lane16;
                    const bool real = (colbase + ncol) < p.nreal;
#pragma unroll
                    for (int r = 0; r < 4; ++r) {
                        const int m = wm + mi * 16 + quad * 4 + r;
                        bounce[m * 66 + ncol] = real ? acc[mi][ni][r] : 0.f;
                    }
                }
        }
        __syncthreads();
#pragma unroll
        for (int i = 0; i < 4; ++i) {
            const int g = i * 256 + tid;
            const int kgl = g >> 7;
            const int m = g & 127;
            float x[8];
#pragma unroll
            for (int j = 0; j < 8; ++j) x[j] = bounce[m * 66 + kgl * 8 + j];
            Yout[((colbase >> 3) + kgl) * 128 + m] = pack8_fp8(x, 4.0f);
        }
    }
}

// ---------------- pipelined fp8 exp-sum GEMM, BN=256 ----------------
struct ExpDesc {
    const unsigned char* A;   // fp8 Y, granule-tile layout (128-row tiles)
    const unsigned char* W;   // fp8 W, granule-tile layout (128-row tiles)
    const float* bias;        // padded, pre-scaled by log2e
    float* part;              // [G][1024]
    int Kpad; int ksl; int kmask; int gy_begin; int slab;  // slab in 256-row dtiles
};

__global__ __launch_bounds__(256) void exp_gemm(ExpDesc d0, ExpDesc d1, ExpDesc d2, ExpDesc d3)
{
    __shared__ u64 As[2][1024];   // 8 KB / slot
    __shared__ u64 Bs[2][2048];   // 16 KB / slot (two 128-row tiles)
    __shared__ float buf[128][2];

    const int gy = blockIdx.y;
    ExpDesc d = (gy >= d3.gy_begin) ? d3 : (gy >= d2.gy_begin) ? d2
              : (gy >= d1.gy_begin) ? d1 : d0;

    const int tid = threadIdx.x;
    const int w = tid >> 6;
    const int l = tid & 63;
    const int mt = blockIdx.x;
    const int wm = (w >> 1) * 64;
    const int wn = (w & 1) * 64;
    const int lane16 = l & 15;
    const int quad = l >> 4;

    const int dt_begin = (gy - d.gy_begin) * d.slab;
    const int T = d.slab << d.ksl;
    const int kmask = d.kmask;
    const int ksl = d.ksl;

    const size_t tstride = (size_t)128 * d.Kpad;
    const unsigned char* Abase = d.A + (size_t)mt * tstride;
    const unsigned char* Bbase = d.W + (size_t)(2 * dt_begin) * tstride;

    const int so0 = tid * 16;
    const int so1 = so0 + 4096;

    // col within dtile for each ni (bias/epilogue mapping)
    int col8[8];
#pragma unroll
    for (int ni = 0; ni < 8; ++ni)
        col8[ni] = (ni >> 2) * 128 + wn + (ni & 3) * 16 + lane16;

    // prologue: iter 0 -> slot 0
    load_lds16(Abase + so0, (char*)As[0] + so0);
    load_lds16(Abase + so1, (char*)As[0] + so1);
    load_lds16(Bbase + so0, (char*)Bs[0] + so0);
    load_lds16(Bbase + so1, (char*)Bs[0] + so1);
    load_lds16(Bbase + tstride + so0, (char*)Bs[0] + 8192 + so0);
    load_lds16(Bbase + tstride + so1, (char*)Bs[0] + 8192 + so1);

    float biasc[8], biasn[8];
#pragma unroll
    for (int ni = 0; ni < 8; ++ni)
        biasc[ni] = d.bias[dt_begin * 256 + col8[ni]];
#pragma unroll
    for (int ni = 0; ni < 8; ++ni) biasn[ni] = 0.f;

    f32x4 acc[4][8] = {};
    float rowsum[4][4] = {};
    const float c1 = LOG2E / 64.0f;   // undo fp8 scales (4*16), e->2^

    for (int it = 0; it < T; ++it) {
        const int slot = it & 1;
        __syncthreads();

        if (it + 1 < T) {
            const int ns = slot ^ 1;
            const int kc = (it + 1) & kmask;
            const int dtn = (it + 1) >> ksl;
            if (kmask) {
                const unsigned char* ac = Abase + kc * 8192;
                load_lds16(ac + so0, (char*)As[ns] + so0);
                load_lds16(ac + so1, (char*)As[ns] + so1);
            }
            const unsigned char* bt = Bbase + (size_t)(2 * dtn) * tstride + kc * 8192;
            load_lds16(bt + so0, (char*)Bs[ns] + so0);
            load_lds16(bt + so1, (char*)Bs[ns] + so1);
            load_lds16(bt + tstride + so0, (char*)Bs[ns] + 8192 + so0);
            load_lds16(bt + tstride + so1, (char*)Bs[ns] + 8192 + so1);
            if (kc == 0) {
#pragma unroll
                for (int ni = 0; ni < 8; ++ni)
                    biasn[ni] = d.bias[(dt_begin + dtn) * 256 + col8[ni]];
            }
        }

        const u64* Ar = As[kmask ? slot : 0];
        const u64* Br = Bs[slot];
#pragma unroll
        for (int ks = 0; ks < 2; ++ks) {
            u64 af[4], bfr[8];
#pragma unroll
            for (int mi = 0; mi < 4; ++mi)
                af[mi] = Ar[(ks * 4 + quad) * 128 + wm + mi * 16 + lane16];
#pragma unroll
            for (int ni = 0; ni < 8; ++ni)
                bfr[ni] = Br[(ni >> 2) * 1024 + (ks * 4 + quad) * 128 + wn + (ni & 3) * 16 + lane16];
#pragma unroll
            for (int mi = 0; mi < 4; ++mi)
#pragma unroll
                for (int ni = 0; ni < 8; ++ni)
                    acc[mi][ni] = __builtin_amdgcn_mfma_f32_16x16x32_fp8_fp8(
                        (long)af[mi], (long)bfr[ni], acc[mi][ni], 0, 0, 0);
        }

        if ((it & kmask) == kmask) {
#pragma unroll
            for (int mi = 0; mi < 4; ++mi)
#pragma unroll
                for (int r = 0; r < 4; ++r) {
                    float s = exp2f(fmaf(acc[mi][0][r], c1, biasc[0]))
                            + exp2f(fmaf(acc[mi][1][r], c1, biasc[1]))
                            + exp2f(fmaf(acc[mi][2][r], c1, biasc[2]))
                            + exp2f(fmaf(acc[mi][3][r], c1, biasc[3]))
                            + exp2f(fmaf(acc[mi][4][r], c1, biasc[4]))
                            + exp2f(fmaf(acc[mi][5][r], c1, biasc[5]))
                            + exp2f(fmaf(acc[mi][6][r], c1, biasc[6]))
                            + exp2f(fmaf(acc[mi][7][r], c1, biasc[7]));
                    rowsum[mi][r] += s;
                }
#pragma unroll
            for (int mi = 0; mi < 4; ++mi)
#pragma unroll
                for (int ni = 0; ni < 8; ++ni)
                    acc[mi][ni] = (f32x4){0.f, 0.f, 0.f, 0.f};
#pragma unroll
            for (int ni = 0; ni < 8; ++ni) biasc[ni] = biasn[ni];
        }
    }

#pragma unroll
    for (int off = 1; off < 16; off <<= 1)
#pragma unroll
        for (int mi = 0; mi < 4; ++mi)
#pragma unroll
            for (int r = 0; r < 4; ++r)
                rowsum[mi][r] += __shfl_xor(rowsum[mi][r], off, 64);

    __syncthreads();
    if (lane16 == 0) {
#pragma unroll
        for (int mi = 0; mi < 4; ++mi)
#pragma unroll
            for (int r = 0; r < 4; ++r)
                buf[wm + mi * 16 + quad * 4 + r][wn >> 6] = rowsum[mi][r];
    }
    __syncthreads();
    if (tid < 128)
        d.part[(size_t)(gy - d.gy_begin) * 1024 + mt * 128 + tid] = buf[tid][0] + buf[tid][1];
}

// ---------------- fused partial-reduce + target-logit extraction ----------------
__global__ void redext(const float* __restrict__ p0, const float* __restrict__ p1,
                       const float* __restrict__ p2, const float* __restrict__ p3,
                       float* __restrict__ S,
                       const unsigned short* __restrict__ Y0, const unsigned short* __restrict__ Y1,
                       const unsigned short* __restrict__ Y2, const unsigned short* __restrict__ Y3,
                       const int* __restrict__ target,
                       const float* __restrict__ W0, const float* __restrict__ b0,
                       const float* __restrict__ W1, const float* __restrict__ b1,
                       const float* __restrict__ W2, const float* __restrict__ b2,
                       const float* __restrict__ W3, const float* __restrict__ b3,
                       const float* __restrict__ cw, const float* __restrict__ cb,
                       float* __restrict__ headlogit, float* __restrict__ taillogit)
{
    if (blockIdx.x < 16) {
        const int idx = blockIdx.x * 256 + threadIdx.x;   // [0,4096)
        const int c = idx >> 10, m = idx & 1023;
        const float* p = (c == 0) ? p0 : (c == 1) ? p1 : (c == 2) ? p2 : p3;
        const int G = (c == 0) ? 79 : (c == 1) ? 20 : (c == 2) ? 25 : 53;
        float s = 0.f;
        for (int y = 0; y < G; ++y) s += p[(size_t)y * 1024 + m];
        S[idx] = s;
        return;
    }
    const int token = (blockIdx.x - 16) * 4 + (threadIdx.x >> 6);
    const int lane = threadIdx.x & 63;
    const int tgt = target[token];
    const int ci = (tgt < 20000) ? 0 : (tgt < 40000) ? 1 : (tgt < 200000) ? 2 : 3;

    {
        const int h = (ci == 0) ? tgt : (20000 + ci - 1);
        const float* row;
        float bb;
        if (h < 20000) { row = W0 + (size_t)h * 1024; bb = b0[h]; }
        else           { row = cw + (size_t)(h - 20000) * 1024; bb = cb[h - 20000]; }
        const unsigned short* y = Y0 + (size_t)token * 1024;
        float s = 0.f;
        for (int k = lane; k < 1024; k += 64) s += bf2f(y[k]) * row[k];
#pragma unroll
        for (int off = 1; off < 64; off <<= 1) s += __shfl_xor(s, off, 64);
        if (lane == 0) headlogit[token] = s + bb;
    }

    float tl = 0.f;
    if (ci > 0) {
        const unsigned short* Y; const float* W; const float* b; int K, ldy, lidx;
        if (ci == 1)      { Y = Y1; W = W1; b = b1; K = 256; ldy = 256; lidx = 20000; }
        else if (ci == 2) { Y = Y2; W = W2; b = b2; K = 64;  ldy = 64;  lidx = 40000; }
        else              { Y = Y3; W = W3; b = b3; K = 16;  ldy = 64;  lidx = 200000; }
        const int r = tgt - lidx;
        const unsigned short* y = Y + (size_t)token * ldy;
        const float* row = W + (size_t)r * K;
        float s = 0.f;
        for (int k = lane; k < K; k += 64) s += bf2f(y[k]) * row[k];
#pragma unroll
        for (int off = 1; off < 64; off <<= 1) s += __shfl_xor(s, off, 64);
        tl = s + b[r];
    }
    if (lane == 0) taillogit[token] = tl;
}

__global__ void finalize_kernel(const float* __restrict__ S,
                                const int* __restrict__ target,
                                const float* __restrict__ headlogit,
                                const float* __restrict__ taillogit,
                                float* __restrict__ out)
{
    __shared__ float red[256];
    const int tid = threadIdx.x;
    float acc = 0.f;
    for (int token = tid; token < 1024; token += 256) {
        const int tgt = target[token];
        const int ci = (tgt < 20000) ? 0 : (tgt < 40000) ? 1 : (tgt < 200000) ? 2 : 3;
        float lp = headlogit[token] - logf(S[token]);
        if (ci > 0)
            lp += taillogit[token] - logf(S[ci * 1024 + token]);
        acc -= lp;
    }
    red[tid] = acc;
    __syncthreads();
    for (int s = 128; s > 0; s >>= 1) {
        if (tid < s) red[tid] += red[tid + s];
        __syncthreads();
    }
    if (tid == 0) out[0] = red[0] * (1.0f / 1024.0f);
}

extern "C" void kernel_launch(void* const* d_in, const int* in_sizes, int n_in,
                              void* d_out, int out_size, void* d_ws, size_t ws_size,
                              hipStream_t stream)
{
    const float* hidden = (const float*)d_in[0];
    const int*   target = (const int*)d_in[1];
    const float* W0 = (const float*)d_in[2];  const float* b0 = (const float*)d_in[3];  const float* P0 = (const float*)d_in[4];
    const float* W1 = (const float*)d_in[5];  const float* b1 = (const float*)d_in[6];  const float* P1 = (const float*)d_in[7];
    const float* W2 = (const float*)d_in[8];  const float* b2 = (const float*)d_in[9];  const float* P2 = (const float*)d_in[10];
    const float* W3 = (const float*)d_in[11]; const float* b3 = (const float*)d_in[12]; const float* P3 = (const float*)d_in[13];
    const float* cw = (const float*)d_in[14]; const float* cb = (const float*)d_in[15];
    float* out = (float*)d_out;

    // ---- workspace layout (byte offsets) ----
    unsigned char* ws = (unsigned char*)d_ws;
    float* part0 = (float*)ws;                       // 79*4096
    float* part1 = part0 + (size_t)79 * 1024;        // 20*4096
    float* part2 = part1 + (size_t)20 * 1024;        // 25*4096
    float* part3 = part2 + (size_t)25 * 1024;        // 53*4096
    float* S = part3 + (size_t)53 * 1024;            // 4*1024
    float* headlogit = S + 4096;
    float* taillogit = headlogit + 1024;
    unsigned short* Y0bf = (unsigned short*)(ws + 1048576);   // 2,097,152
    unsigned short* Y1bf = (unsigned short*)(ws + 3145728);   //   524,288
    unsigned short* Y2bf = (unsigned short*)(ws + 3670016);   //   131,072
    unsigned short* Y3bf = (unsigned short*)(ws + 3801088);   //   131,072
    unsigned char* Y0f8 = ws + 3932160;                       // 1,048,576
    unsigned char* Y1f8 = ws + 4980736;                       //   262,144
    unsigned char* Y2f8 = ws + 5242880;                       //    65,536
    unsigned char* Y3f8 = ws + 5308416;                       //    65,536
    unsigned char* Wb0 = ws + 5372928;                        // 20224*1024
    unsigned char* Wb1 = ws + 26082304;                       // 20480*256
    unsigned char* Wb2 = ws + 31325184;                       // 160000*64
    unsigned char* Wb3 = ws + 41565184;                       // 67840*64
    float* bp = (float*)(ws + 45906944);                      // 268544 floats

    ProjDesc pr0 = { P0, Y0bf, Y0f8, 1024, 1024, 1024, 1024, 0 };
    ProjDesc pr1 = { P1, Y1bf, Y1f8, 256,  256,  256,  256,  8 };
    ProjDesc pr2 = { P2, Y2bf, Y2f8, 64,   64,   64,   64,   10 };
    ProjDesc pr3 = { P3, Y3bf, Y3f8, 64,   16,   16,   64,   11 };
    prepproj<<<10255, 256, 0, stream>>>(hidden, pr0, pr1, pr2, pr3,
                                        W0, cw, W1, W2, W3,
                                        b0, cb, b1, b2, b3,
                                        Wb0, Wb1, Wb2, Wb3, bp);

    // dtiles: head 79 (Npad 20224), t1 80 (20480), t2 625 (160000), t3 265 (67840)
    ExpDesc d0 = { Y0f8, Wb0, bp,          part0, 1024, 4, 15, 0,   1 };
    ExpDesc d1 = { Y1f8, Wb1, bp + 20224,  part1, 256,  2, 3,  79,  4 };
    ExpDesc d2 = { Y2f8, Wb2, bp + 40704,  part2, 64,   0, 0,  99,  25 };
    ExpDesc d3 = { Y3f8, Wb3, bp + 200704, part3, 64,   0, 0,  124, 5 };
    exp_gemm<<<dim3(8, 177), 256, 0, stream>>>(d0, d1, d2, d3);

    redext<<<272, 256, 0, stream>>>(part0, part1, part2, part3, S,
                                    Y0bf, Y1bf, Y2bf, Y3bf, target,
                                    W0, b0, W1, b1, W2, b2, W3, b3,
                                    cw, cb, headlogit, taillogit);

    finalize_kernel<<<1, 256, 0, stream>>>(S, target, headlogit, taillogit, out);
}